// Round 3
// baseline (296.661 us; speedup 1.0000x reference)
//
#include <hip/hip_runtime.h>
#include <hip/hip_bf16.h>

using bf16 = __hip_bfloat16;
typedef __attribute__((ext_vector_type(8))) short short8;     // 8 bf16 MFMA a/b frag
typedef __attribute__((ext_vector_type(4))) float floatx4;    // 16x16 MFMA c/d frag
typedef __attribute__((ext_vector_type(16))) float floatx16;  // 32x32 MFMA c/d frag

#define NEG_INF (-__builtin_huge_valf())

// async global->LDS, 16B per lane. LDS dest is wave-uniform base + lane*16.
__device__ __forceinline__ void gld_lds16(const void* g, void* l) {
  __builtin_amdgcn_global_load_lds(
      (const __attribute__((address_space(1))) unsigned int*)g,
      (__attribute__((address_space(3))) unsigned int*)l, 16, 0, 0);
}

template <int N> __device__ __forceinline__ void wait_vm() {
  asm volatile("s_waitcnt vmcnt(%0)" ::"n"(N) : "memory");
}
__device__ __forceinline__ void bar() {
  asm volatile("" ::: "memory");
  __builtin_amdgcn_s_barrier();
  asm volatile("" ::: "memory");
}

__device__ __forceinline__ void cvt8(const float4& a, const float4& b, bf16* t) {
  t[0] = __float2bfloat16(a.x); t[1] = __float2bfloat16(a.y);
  t[2] = __float2bfloat16(a.z); t[3] = __float2bfloat16(a.w);
  t[4] = __float2bfloat16(b.x); t[5] = __float2bfloat16(b.y);
  t[6] = __float2bfloat16(b.z); t[7] = __float2bfloat16(b.w);
}

// ---- algebra: logits = [X·M·Y^T + u·1^T + 1·v^T + c]/64,
//      M = qw^T·kw,  u = X·(qw^T kb),  v = Y·(kw^T qb),  c = qb·kb.

// ---------------- prep_small: w1 = qw^T·kb, w2 = kw^T·qb, c = qb·kb --------
__global__ __launch_bounds__(256) void prep_small(const float* __restrict__ qw,
                                                  const float* __restrict__ kw,
                                                  const float* __restrict__ qb,
                                                  const float* __restrict__ kb,
                                                  float* __restrict__ w1,
                                                  float* __restrict__ w2,
                                                  float* __restrict__ cks) {
  const int tid = threadIdx.x;
  if (blockIdx.x == 0) {
    float a0 = 0.f, a1 = 0.f;
    for (int i = 0; i < 512; ++i) {
      const float s = kb[i];
      a0 += qw[(size_t)i * 512 + tid] * s;
      a1 += qw[(size_t)i * 512 + tid + 256] * s;
    }
    w1[tid] = a0; w1[tid + 256] = a1;
    __shared__ float red[256];
    red[tid] = qb[tid] * kb[tid] + qb[tid + 256] * kb[tid + 256];
    __syncthreads();
    for (int s = 128; s > 0; s >>= 1) {
      if (tid < s) red[tid] += red[tid + s];
      __syncthreads();
    }
    if (tid == 0) *cks = red[0];
  } else {
    float a0 = 0.f, a1 = 0.f;
    for (int i = 0; i < 512; ++i) {
      const float s = qb[i];
      a0 += kw[(size_t)i * 512 + tid] * s;
      a1 += kw[(size_t)i * 512 + tid + 256] * s;
    }
    w2[tid] = a0; w2[tid + 256] = a1;
  }
}

// ---------------- prep_m: Mt[n,k] = M[k,n] = sum_i qw[i,k]*kw[i,n], bf16 out
// fp32 outer-product GEMM, 64x64 tile/block, grid (8,8), dbuf 8-row staging.
__global__ __launch_bounds__(256) void prep_m(const float* __restrict__ qw,
                                              const float* __restrict__ kw,
                                              bf16* __restrict__ mtp) {
  __shared__ float skw[2][8][64];   // kw[i, n0+..]   (n side)
  __shared__ float sqw[2][8][64];   // qw[i, k0+..]   (k side)
  const int n0 = blockIdx.y * 64, k0 = blockIdx.x * 64;
  const int tid = threadIdx.x;
  const int tr = tid >> 4, tc = tid & 15;       // 16x16 threads, 4x4 outputs each
  const int sr = tid >> 5, sc = (tid & 31) * 2; // staging: 8 rows x 64 cols, 2/thread
  float acc[4][4];
  #pragma unroll
  for (int x = 0; x < 4; ++x)
    #pragma unroll
    for (int y = 0; y < 4; ++y) acc[x][y] = 0.f;

  auto stage = [&](int buf, int i0) {
    float2 kv = *(const float2*)&kw[(size_t)(i0 + sr) * 512 + n0 + sc];
    float2 qv = *(const float2*)&qw[(size_t)(i0 + sr) * 512 + k0 + sc];
    skw[buf][sr][sc] = kv.x; skw[buf][sr][sc + 1] = kv.y;
    sqw[buf][sr][sc] = qv.x; sqw[buf][sr][sc + 1] = qv.y;
  };
  stage(0, 0);
  __syncthreads();
  for (int cb = 0; cb < 64; ++cb) {
    if (cb < 63) stage((cb + 1) & 1, (cb + 1) * 8);
    const int buf = cb & 1;
    #pragma unroll
    for (int ii = 0; ii < 8; ++ii) {
      float av[4], bv[4];
      #pragma unroll
      for (int x = 0; x < 4; ++x) av[x] = skw[buf][ii][tr * 4 + x];
      #pragma unroll
      for (int y = 0; y < 4; ++y) bv[y] = sqw[buf][ii][tc * 4 + y];
      #pragma unroll
      for (int x = 0; x < 4; ++x)
        #pragma unroll
        for (int y = 0; y < 4; ++y) acc[x][y] += av[x] * bv[y];
    }
    __syncthreads();
  }
  #pragma unroll
  for (int x = 0; x < 4; ++x)
    #pragma unroll
    for (int y = 0; y < 4; ++y)
      mtp[(size_t)(n0 + tr * 4 + x) * 512 + k0 + tc * 4 + y] =
          __float2bfloat16(acc[x][y]);
}

// ---------------- cvt_in: fp32->bf16 for X ++ Y, fused u/v row-dots --------
// 12582912 elems = 6144 blocks * 2048. Each wave covers exactly one 512-row.
__global__ __launch_bounds__(256) void cvt_in(const float* __restrict__ q,
                                              const float* __restrict__ k,
                                              const float* __restrict__ w1,
                                              const float* __restrict__ w2,
                                              const float* __restrict__ cks,
                                              bf16* __restrict__ qo, bf16* __restrict__ ko,
                                              float* __restrict__ u, float* __restrict__ v) {
  const size_t e = ((size_t)blockIdx.x * 256 + threadIdx.x) * 8;
  const bool isX = e < 4194304;
  const float* src = isX ? q + e : k + (e - 4194304);
  bf16*        dst = isX ? qo + e : ko + (e - 4194304);
  const float* wv  = (isX ? w1 : w2) + (int)(e & 511);

  float4 a = *(const float4*)src;
  float4 c = *(const float4*)(src + 4);
  bf16 t[8];
  cvt8(a, c, t);
  *(short8*)dst = *(short8*)t;

  float4 wa = *(const float4*)wv;
  float4 wb = *(const float4*)(wv + 4);
  float p = a.x * wa.x + a.y * wa.y + a.z * wa.z + a.w * wa.w +
            c.x * wb.x + c.y * wb.y + c.z * wb.z + c.w * wb.w;
  #pragma unroll
  for (int d = 1; d < 64; d <<= 1) p += __shfl_xor(p, d, 64);
  if ((threadIdx.x & 63) == 0) {
    const size_t row = e >> 9;
    if (isX) u[row] = p + *cks;
    else     v[row - 8192] = p;
  }
}

// 32x32x16 MFMA block: wave covers 64x64 as 2x2 of 32x32 tiles.
// A/B operand: m|n = lane&31, k = (lane>>5)*8 + j  (row-major [rows][32] LDS tile)
// C/D: col = lane&31, row = (reg&3) + 8*(reg>>2) + 4*(lane>>5)   [m74/m101]
__device__ __forceinline__ void mfma_tile32(const bf16* sAh, const bf16* sBh,
                                            int wm, int wn, int lane,
                                            floatx16 acc[2][2]) {
  const int fm = lane & 31;
  const int fk = (lane >> 5) * 8;
  #pragma unroll
  for (int ks = 0; ks < 2; ++ks) {
    short8 a0 = *(const short8*)(sAh + (wm +  0 + fm) * 32 + ks * 16 + fk);
    short8 a1 = *(const short8*)(sAh + (wm + 32 + fm) * 32 + ks * 16 + fk);
    short8 b0 = *(const short8*)(sBh + (wn +  0 + fm) * 32 + ks * 16 + fk);
    short8 b1 = *(const short8*)(sBh + (wn + 32 + fm) * 32 + ks * 16 + fk);
    acc[0][0] = __builtin_amdgcn_mfma_f32_32x32x16_bf16(a0, b0, acc[0][0], 0, 0, 0);
    acc[0][1] = __builtin_amdgcn_mfma_f32_32x32x16_bf16(a0, b1, acc[0][1], 0, 0, 0);
    acc[1][0] = __builtin_amdgcn_mfma_f32_32x32x16_bf16(a1, b0, acc[1][0], 0, 0, 0);
    acc[1][1] = __builtin_amdgcn_mfma_f32_32x32x16_bf16(a1, b1, acc[1][1], 0, 0, 0);
  }
}

// ---------------- zgemm: Z = Xbf · Mt^T (bf16 out), 128x128 tile, grid (64,4)
__global__ __launch_bounds__(256) void zgemm(const bf16* __restrict__ X,
                                             const bf16* __restrict__ Mt,
                                             bf16* __restrict__ Z) {
  __shared__ bf16 sA[2][128 * 32];
  __shared__ bf16 sB[2][128 * 32];
  const int m0 = blockIdx.x * 128;
  const int n0 = blockIdx.y * 128;

  const int tid  = threadIdx.x;
  const int lane = tid & 63;
  const int w    = tid >> 6;
  const int wm   = (w >> 1) * 64;
  const int wn   = (w & 1) * 64;
  const int st_row = lane >> 2;
  const int st_col = (lane & 3) * 8;

  floatx16 acc[2][2];
  #pragma unroll
  for (int mi = 0; mi < 2; ++mi)
    #pragma unroll
    for (int ni = 0; ni < 2; ++ni)
      #pragma unroll
      for (int r = 0; r < 16; ++r)
        acc[mi][ni][r] = 0.f;

  for (int kt = 0; kt < 512; kt += 64) {
    #pragma unroll
    for (int h = 0; h < 2; ++h)
      #pragma unroll
      for (int j = 0; j < 2; ++j) {
        const int r = (w << 5) + (j << 4);
        gld_lds16(X  + (size_t)(m0 + r + st_row) * 512 + kt + h * 32 + st_col,
                  &sA[h][r * 32]);
        gld_lds16(Mt + (size_t)(n0 + r + st_row) * 512 + kt + h * 32 + st_col,
                  &sB[h][r * 32]);
      }
    __syncthreads();
    #pragma unroll
    for (int h = 0; h < 2; ++h)
      mfma_tile32(sA[h], sB[h], wm, wn, lane, acc);
    __syncthreads();
  }

  const int col = lane & 31;
  const int rhi = (lane >> 5) * 4;
  #pragma unroll
  for (int ni = 0; ni < 2; ++ni) {
    const int gn = n0 + wn + ni * 32 + col;
    #pragma unroll
    for (int mi = 0; mi < 2; ++mi)
      #pragma unroll
      for (int reg = 0; reg < 16; ++reg) {
        const int row = (reg & 3) + 8 * (reg >> 2) + rhi;
        Z[(size_t)(m0 + wm + mi * 32 + row) * 512 + gn] =
            __float2bfloat16(acc[mi][ni][reg]);
      }
  }
}

// ---------------- out = [Z·Y^T + u + v]/64, mask -> -inf -------------------
// 256x256 tile, BK=64, 8 waves, 8-phase counted-vmcnt schedule (unchanged R2).
__global__ __launch_bounds__(512, 2) void qk8(const bf16* __restrict__ Q,
                                              const bf16* __restrict__ Kp,
                                              const unsigned char* __restrict__ mask,
                                              const float* __restrict__ u,
                                              const float* __restrict__ v,
                                              float* __restrict__ out) {
  __shared__ alignas(16) char smem[2][4][16384];   // 128 KiB

  const int bid = blockIdx.x;
  const int sb  = ((bid & 7) << 6) | (bid >> 3);   // bijective XCD swizzle (512%8==0)
  const int b   = sb >> 7;
  const int mt  = (sb >> 4) & 7;
  const int nt  = sb & 15;

  const bf16* Qb = Q  + ((size_t)b * 2048 + (size_t)mt * 256) * 512;
  const bf16* Kb = Kp + ((size_t)b * 4096 + (size_t)nt * 256) * 512;

  const int tid  = threadIdx.x;
  const int lane = tid & 63;
  const int w    = tid >> 6;       // wave 0..7
  const int wm   = w >> 2;         // 0..1  (M half: 128 rows)
  const int wn   = w & 3;          // 0..3  (N quarter: 64 cols)
  const int l15  = lane & 15;
  const int kg   = lane >> 4;      // 0..3
  const int aoff = l15 * 64 + ((kg << 4) ^ ((l15 & 8) << 2) ^ ((l15 & 2) << 3));

  auto stage_kh = [&](int t, int kh) {
    const int kt  = t * 64;
    char* dst = &smem[t & 1][0][0] + (w * 2 + kh) * 1024;
    const int r   = (w << 4) | (lane >> 2);
    const int swz = ((r & 8) << 2) ^ ((r & 2) << 3);
    const int cby = (kh << 6) | ((((lane & 3) << 4)) ^ swz);
    const int gc  = kt + (cby >> 1);
    gld_lds16(Qb + (size_t)(      r) * 512 + gc, dst);
    gld_lds16(Qb + (size_t)(128 + r) * 512 + gc, dst + 16384);
    gld_lds16(Kb + (size_t)(      r) * 512 + gc, dst + 32768);
    gld_lds16(Kb + (size_t)(128 + r) * 512 + gc, dst + 49152);
  };

  floatx4 acc[8][4];
  #pragma unroll
  for (int i = 0; i < 8; ++i)
    #pragma unroll
    for (int j = 0; j < 4; ++j)
      acc[i][j] = (floatx4){0.f, 0.f, 0.f, 0.f};

  stage_kh(0, 0); stage_kh(0, 1); stage_kh(1, 0);
  wait_vm<4>();
  bar();

  #pragma unroll
  for (int t = 0; t < 8; ++t) {
    const char* Ah = &smem[t & 1][wm][0];
    const char* Bh = &smem[t & 1][2 + (wn >> 1)][0] + (wn & 1) * 8192;
    #pragma unroll
    for (int kh = 0; kh < 2; ++kh) {
      short8 a[4], bb[4];
      if (kh == 0) { if (t < 7) stage_kh(t + 1, 1); }
      else         { if (t < 6) stage_kh(t + 2, 0); }
      #pragma unroll
      for (int fr = 0; fr < 4; ++fr)
        a[fr] = *(const short8*)(Ah + fr * 2048 + kh * 1024 + aoff);
      #pragma unroll
      for (int fn = 0; fn < 4; ++fn)
        bb[fn] = *(const short8*)(Bh + fn * 2048 + kh * 1024 + aoff);
      bar();
      asm volatile("s_waitcnt lgkmcnt(0)" ::: "memory");
      __builtin_amdgcn_sched_barrier(0);
      __builtin_amdgcn_s_setprio(1);
      #pragma unroll
      for (int fr = 0; fr < 4; ++fr)
        #pragma unroll
        for (int fn = 0; fn < 4; ++fn)
          acc[fr][fn] = __builtin_amdgcn_mfma_f32_16x16x32_bf16(
              a[fr], bb[fn], acc[fr][fn], 0, 0, 0);
      __builtin_amdgcn_s_setprio(0);
      bar();
      #pragma unroll
      for (int fr = 0; fr < 4; ++fr)
        a[fr] = *(const short8*)(Ah + (4 + fr) * 2048 + kh * 1024 + aoff);
      bar();
      asm volatile("s_waitcnt lgkmcnt(0)" ::: "memory");
      __builtin_amdgcn_sched_barrier(0);
      __builtin_amdgcn_s_setprio(1);
      #pragma unroll
      for (int fr = 0; fr < 4; ++fr)
        #pragma unroll
        for (int fn = 0; fn < 4; ++fn)
          acc[4 + fr][fn] = __builtin_amdgcn_mfma_f32_16x16x32_bf16(
              a[fr], bb[fn], acc[4 + fr][fn], 0, 0, 0);
      __builtin_amdgcn_s_setprio(0);
      if (kh == 1) {
        if (t < 6)       wait_vm<4>();
        else if (t == 6) wait_vm<0>();
      }
      bar();
    }
  }

  // epilogue: out = (acc + u[row] + v[col]) / 64, mask -> -inf
  float* ob = out + (size_t)b * 2048 * 4096
                  + ((size_t)mt * 256 + (size_t)wm * 128) * 4096
                  + (size_t)nt * 256 + wn * 64;
  const unsigned char* mb = mask + (size_t)b * 4096 + nt * 256 + wn * 64;
  const float* ub = u + (size_t)b * 2048 + mt * 256 + wm * 128;
  const float* vb = v + (size_t)b * 4096 + nt * 256 + wn * 64;
  float ur[8][4];
  #pragma unroll
  for (int f8 = 0; f8 < 8; ++f8)
    #pragma unroll
    for (int r = 0; r < 4; ++r)
      ur[f8][r] = ub[f8 * 16 + kg * 4 + r];
  #pragma unroll
  for (int fc = 0; fc < 4; ++fc) {
    const int c = fc * 16 + l15;
    const bool msk = mb[c] != 0;
    const float vc = vb[c];
    #pragma unroll
    for (int f8 = 0; f8 < 8; ++f8)
      #pragma unroll
      for (int r = 0; r < 4; ++r)
        ob[(size_t)(f8 * 16 + kg * 4 + r) * 4096 + c] =
            msk ? NEG_INF : (acc[f8][fc][r] + ur[f8][r] + vc) * (1.f / 64.f);
  }
}

extern "C" void kernel_launch(void* const* d_in, const int* in_sizes, int n_in,
                              void* d_out, int out_size, void* d_ws, size_t ws_size,
                              hipStream_t stream) {
  const float* query = (const float*)d_in[0];
  const float* keys  = (const float*)d_in[1];
  const unsigned char* mask = (const unsigned char*)d_in[2];  // numpy bool = 1B
  const float* q_w = (const float*)d_in[3];
  const float* q_b = (const float*)d_in[4];
  const float* k_w = (const float*)d_in[5];
  const float* k_b = (const float*)d_in[6];
  float* out = (float*)d_out;

  // workspace carve, ~34.2 MiB
  char* ws = (char*)d_ws;
  bf16*  x_bf  = (bf16*)(ws);                        //  8192*512 bf16
  bf16*  y_bf  = (bf16*)(ws + 8388608);              // 16384*512 bf16
  bf16*  mt_bf = (bf16*)(ws + 25165824);             //   512*512 bf16
  bf16*  z_bf  = (bf16*)(ws + 25690112);             //  8192*512 bf16
  float* u     = (float*)(ws + 34078720);            //  8192 f32
  float* v     = (float*)(ws + 34111488);            // 16384 f32
  float* w1    = (float*)(ws + 34177024);            //   512 f32
  float* w2    = (float*)(ws + 34179072);            //   512 f32
  float* cks   = (float*)(ws + 34181120);            //     1 f32

  prep_small<<<2, 256, 0, stream>>>(q_w, k_w, q_b, k_b, w1, w2, cks);
  prep_m<<<dim3(8, 8), 256, 0, stream>>>(q_w, k_w, mt_bf);
  cvt_in<<<6144, 256, 0, stream>>>(query, keys, w1, w2, cks, x_bf, y_bf, u, v);
  zgemm<<<dim3(64, 4), 256, 0, stream>>>(x_bf, mt_bf, z_bf);
  qk8<<<512, 512, 0, stream>>>(z_bf, y_bf, mask, u, v, out);
}

// Round 4
// 275.992 us; speedup vs baseline: 1.0749x; 1.0749x over previous
//
#include <hip/hip_runtime.h>
#include <hip/hip_bf16.h>

using bf16 = __hip_bfloat16;
typedef __attribute__((ext_vector_type(8))) short short8;     // 8 bf16 MFMA a/b frag
typedef __attribute__((ext_vector_type(4))) float floatx4;    // 16x16 MFMA c/d frag
typedef __attribute__((ext_vector_type(16))) float floatx16;  // 32x32 MFMA c/d frag

#define NEG_INF (-__builtin_huge_valf())

// async global->LDS, 16B per lane. LDS dest is wave-uniform base + lane*16.
__device__ __forceinline__ void gld_lds16(const void* g, void* l) {
  __builtin_amdgcn_global_load_lds(
      (const __attribute__((address_space(1))) unsigned int*)g,
      (__attribute__((address_space(3))) unsigned int*)l, 16, 0, 0);
}

template <int N> __device__ __forceinline__ void wait_vm() {
  asm volatile("s_waitcnt vmcnt(%0)" ::"n"(N) : "memory");
}
__device__ __forceinline__ void bar() {
  asm volatile("" ::: "memory");
  __builtin_amdgcn_s_barrier();
  asm volatile("" ::: "memory");
}

__device__ __forceinline__ void cvt8(const float4& a, const float4& b, bf16* t) {
  t[0] = __float2bfloat16(a.x); t[1] = __float2bfloat16(a.y);
  t[2] = __float2bfloat16(a.z); t[3] = __float2bfloat16(a.w);
  t[4] = __float2bfloat16(b.x); t[5] = __float2bfloat16(b.y);
  t[6] = __float2bfloat16(b.z); t[7] = __float2bfloat16(b.w);
}

// ---- algebra: logits = [X·M·Y^T + u·1^T + 1·v^T + c]/64,
//      M = qw^T·kw,  u = X·(qw^T kb),  v = Y·(kw^T qb),  c = qb·kb.

// ---------------- prep (fused, 80 blocks):
//   blocks 0-63 : Mt[n,k] = M[k,n] = sum_i qw[i,k]*kw[i,n]  (bf16 out, 64x64 tile)
//   blocks 64-79: w1 = qw^T·kb (8 blocks) / w2 = kw^T·qb (8 blocks),
//                 64 cols/block, 4 waves x 128 i each, LDS cross-wave reduce.
//   block 64 also computes c = qb·kb.
__global__ __launch_bounds__(256) void prep(const float* __restrict__ qw,
                                            const float* __restrict__ kw,
                                            const float* __restrict__ qb,
                                            const float* __restrict__ kb,
                                            bf16* __restrict__ mtp,
                                            float* __restrict__ w1,
                                            float* __restrict__ w2,
                                            float* __restrict__ cks) {
  __shared__ float pool[2][2][8][64];   // 8 KiB, reused by both halves
  const int bid = blockIdx.x;
  const int tid = threadIdx.x;

  if (bid < 64) {
    float (*skw)[8][64] = pool[0];      // kw[i, n0+..]
    float (*sqw)[8][64] = pool[1];      // qw[i, k0+..]
    const int n0 = (bid >> 3) * 64, k0 = (bid & 7) * 64;
    const int tr = tid >> 4, tc = tid & 15;
    const int sr = tid >> 5, sc = (tid & 31) * 2;
    float acc[4][4];
    #pragma unroll
    for (int x = 0; x < 4; ++x)
      #pragma unroll
      for (int y = 0; y < 4; ++y) acc[x][y] = 0.f;

    auto stage = [&](int buf, int i0) {
      float2 kv = *(const float2*)&kw[(size_t)(i0 + sr) * 512 + n0 + sc];
      float2 qv = *(const float2*)&qw[(size_t)(i0 + sr) * 512 + k0 + sc];
      skw[buf][sr][sc] = kv.x; skw[buf][sr][sc + 1] = kv.y;
      sqw[buf][sr][sc] = qv.x; sqw[buf][sr][sc + 1] = qv.y;
    };
    stage(0, 0);
    __syncthreads();
    for (int cb = 0; cb < 64; ++cb) {
      if (cb < 63) stage((cb + 1) & 1, (cb + 1) * 8);
      const int buf = cb & 1;
      #pragma unroll
      for (int ii = 0; ii < 8; ++ii) {
        float av[4], bv[4];
        #pragma unroll
        for (int x = 0; x < 4; ++x) av[x] = skw[buf][ii][tr * 4 + x];
        #pragma unroll
        for (int y = 0; y < 4; ++y) bv[y] = sqw[buf][ii][tc * 4 + y];
        #pragma unroll
        for (int x = 0; x < 4; ++x)
          #pragma unroll
          for (int y = 0; y < 4; ++y) acc[x][y] += av[x] * bv[y];
      }
      __syncthreads();
    }
    #pragma unroll
    for (int x = 0; x < 4; ++x)
      #pragma unroll
      for (int y = 0; y < 4; ++y)
        mtp[(size_t)(n0 + tr * 4 + x) * 512 + k0 + tc * 4 + y] =
            __float2bfloat16(acc[x][y]);
  } else {
    const int bid2 = bid - 64;          // 0..15
    const bool isW1 = bid2 < 8;
    const float* src = isW1 ? qw : kw;
    const float* vec = isW1 ? kb : qb;
    float* outp      = isW1 ? w1 : w2;
    const int j = ((bid2 & 7) << 6) | (tid & 63);
    const int q = tid >> 6;             // wave id, i-quarter
    float p = 0.f;
    #pragma unroll 8
    for (int i = q * 128; i < q * 128 + 128; ++i)
      p += src[(size_t)i * 512 + j] * vec[i];
    float* red = &pool[0][0][0][0];
    red[tid] = p;
    __syncthreads();
    if (tid < 64)
      outp[j] = red[tid] + red[tid + 64] + red[tid + 128] + red[tid + 192];
    if (bid2 == 0) {                    // block-uniform branch
      __syncthreads();
      red[tid] = qb[tid] * kb[tid] + qb[tid + 256] * kb[tid + 256];
      __syncthreads();
      for (int s = 128; s > 0; s >>= 1) {
        if (tid < s) red[tid] += red[tid + s];
        __syncthreads();
      }
      if (tid == 0) *cks = red[0];
    }
  }
}

// ---------------- cvt_in: fp32->bf16 for X ++ Y, fused u/v row-dots --------
// 12582912 elems = 6144 blocks * 2048. Each wave covers exactly one 512-row.
__global__ __launch_bounds__(256) void cvt_in(const float* __restrict__ q,
                                              const float* __restrict__ k,
                                              const float* __restrict__ w1,
                                              const float* __restrict__ w2,
                                              const float* __restrict__ cks,
                                              bf16* __restrict__ qo, bf16* __restrict__ ko,
                                              float* __restrict__ u, float* __restrict__ v) {
  const size_t e = ((size_t)blockIdx.x * 256 + threadIdx.x) * 8;
  const bool isX = e < 4194304;
  const float* src = isX ? q + e : k + (e - 4194304);
  bf16*        dst = isX ? qo + e : ko + (e - 4194304);
  const float* wv  = (isX ? w1 : w2) + (int)(e & 511);

  float4 a = *(const float4*)src;
  float4 c = *(const float4*)(src + 4);
  bf16 t[8];
  cvt8(a, c, t);
  *(short8*)dst = *(short8*)t;

  float4 wa = *(const float4*)wv;
  float4 wb = *(const float4*)(wv + 4);
  float p = a.x * wa.x + a.y * wa.y + a.z * wa.z + a.w * wa.w +
            c.x * wb.x + c.y * wb.y + c.z * wb.z + c.w * wb.w;
  #pragma unroll
  for (int d = 1; d < 64; d <<= 1) p += __shfl_xor(p, d, 64);
  if ((threadIdx.x & 63) == 0) {
    const size_t row = e >> 9;
    if (isX) u[row] = p + *cks;
    else     v[row - 8192] = p;
  }
}

// 32x32x16 MFMA block: wave covers 64x64 as 2x2 of 32x32 tiles.
// A/B operand: m|n = lane&31, k = (lane>>5)*8 + j  (row-major [rows][32] LDS tile)
// C/D: col = lane&31, row = (reg&3) + 8*(reg>>2) + 4*(lane>>5)   [m74/m101]
__device__ __forceinline__ void mfma_tile32(const bf16* sAh, const bf16* sBh,
                                            int wm, int wn, int lane,
                                            floatx16 acc[2][2]) {
  const int fm = lane & 31;
  const int fk = (lane >> 5) * 8;
  #pragma unroll
  for (int ks = 0; ks < 2; ++ks) {
    short8 a0 = *(const short8*)(sAh + (wm +  0 + fm) * 32 + ks * 16 + fk);
    short8 a1 = *(const short8*)(sAh + (wm + 32 + fm) * 32 + ks * 16 + fk);
    short8 b0 = *(const short8*)(sBh + (wn +  0 + fm) * 32 + ks * 16 + fk);
    short8 b1 = *(const short8*)(sBh + (wn + 32 + fm) * 32 + ks * 16 + fk);
    acc[0][0] = __builtin_amdgcn_mfma_f32_32x32x16_bf16(a0, b0, acc[0][0], 0, 0, 0);
    acc[0][1] = __builtin_amdgcn_mfma_f32_32x32x16_bf16(a0, b1, acc[0][1], 0, 0, 0);
    acc[1][0] = __builtin_amdgcn_mfma_f32_32x32x16_bf16(a1, b0, acc[1][0], 0, 0, 0);
    acc[1][1] = __builtin_amdgcn_mfma_f32_32x32x16_bf16(a1, b1, acc[1][1], 0, 0, 0);
  }
}

// ---------------- zgemm: Z = Xbf · Mt^T (bf16 out), 128x128 tile, grid (64,4)
__global__ __launch_bounds__(256) void zgemm(const bf16* __restrict__ X,
                                             const bf16* __restrict__ Mt,
                                             bf16* __restrict__ Z) {
  __shared__ bf16 sA[2][128 * 32];
  __shared__ bf16 sB[2][128 * 32];
  const int m0 = blockIdx.x * 128;
  const int n0 = blockIdx.y * 128;

  const int tid  = threadIdx.x;
  const int lane = tid & 63;
  const int w    = tid >> 6;
  const int wm   = (w >> 1) * 64;
  const int wn   = (w & 1) * 64;
  const int st_row = lane >> 2;
  const int st_col = (lane & 3) * 8;

  floatx16 acc[2][2];
  #pragma unroll
  for (int mi = 0; mi < 2; ++mi)
    #pragma unroll
    for (int ni = 0; ni < 2; ++ni)
      #pragma unroll
      for (int r = 0; r < 16; ++r)
        acc[mi][ni][r] = 0.f;

  for (int kt = 0; kt < 512; kt += 64) {
    #pragma unroll
    for (int h = 0; h < 2; ++h)
      #pragma unroll
      for (int j = 0; j < 2; ++j) {
        const int r = (w << 5) + (j << 4);
        gld_lds16(X  + (size_t)(m0 + r + st_row) * 512 + kt + h * 32 + st_col,
                  &sA[h][r * 32]);
        gld_lds16(Mt + (size_t)(n0 + r + st_row) * 512 + kt + h * 32 + st_col,
                  &sB[h][r * 32]);
      }
    __syncthreads();
    #pragma unroll
    for (int h = 0; h < 2; ++h)
      mfma_tile32(sA[h], sB[h], wm, wn, lane, acc);
    __syncthreads();
  }

  const int col = lane & 31;
  const int rhi = (lane >> 5) * 4;
  #pragma unroll
  for (int ni = 0; ni < 2; ++ni) {
    const int gn = n0 + wn + ni * 32 + col;
    #pragma unroll
    for (int mi = 0; mi < 2; ++mi)
      #pragma unroll
      for (int reg = 0; reg < 16; ++reg) {
        const int row = (reg & 3) + 8 * (reg >> 2) + rhi;
        Z[(size_t)(m0 + wm + mi * 32 + row) * 512 + gn] =
            __float2bfloat16(acc[mi][ni][reg]);
      }
  }
}

// ---------------- out = [Z·Y^T + u + v]/64, mask -> -inf -------------------
// 256x256 tile, BK=64, 8 waves, 8-phase counted-vmcnt schedule (unchanged R2).
__global__ __launch_bounds__(512, 2) void qk8(const bf16* __restrict__ Q,
                                              const bf16* __restrict__ Kp,
                                              const unsigned char* __restrict__ mask,
                                              const float* __restrict__ u,
                                              const float* __restrict__ v,
                                              float* __restrict__ out) {
  __shared__ alignas(16) char smem[2][4][16384];   // 128 KiB

  const int bid = blockIdx.x;
  const int sb  = ((bid & 7) << 6) | (bid >> 3);   // bijective XCD swizzle (512%8==0)
  const int b   = sb >> 7;
  const int mt  = (sb >> 4) & 7;
  const int nt  = sb & 15;

  const bf16* Qb = Q  + ((size_t)b * 2048 + (size_t)mt * 256) * 512;
  const bf16* Kb = Kp + ((size_t)b * 4096 + (size_t)nt * 256) * 512;

  const int tid  = threadIdx.x;
  const int lane = tid & 63;
  const int w    = tid >> 6;       // wave 0..7
  const int wm   = w >> 2;         // 0..1  (M half: 128 rows)
  const int wn   = w & 3;          // 0..3  (N quarter: 64 cols)
  const int l15  = lane & 15;
  const int kg   = lane >> 4;      // 0..3
  const int aoff = l15 * 64 + ((kg << 4) ^ ((l15 & 8) << 2) ^ ((l15 & 2) << 3));

  auto stage_kh = [&](int t, int kh) {
    const int kt  = t * 64;
    char* dst = &smem[t & 1][0][0] + (w * 2 + kh) * 1024;
    const int r   = (w << 4) | (lane >> 2);
    const int swz = ((r & 8) << 2) ^ ((r & 2) << 3);
    const int cby = (kh << 6) | ((((lane & 3) << 4)) ^ swz);
    const int gc  = kt + (cby >> 1);
    gld_lds16(Qb + (size_t)(      r) * 512 + gc, dst);
    gld_lds16(Qb + (size_t)(128 + r) * 512 + gc, dst + 16384);
    gld_lds16(Kb + (size_t)(      r) * 512 + gc, dst + 32768);
    gld_lds16(Kb + (size_t)(128 + r) * 512 + gc, dst + 49152);
  };

  floatx4 acc[8][4];
  #pragma unroll
  for (int i = 0; i < 8; ++i)
    #pragma unroll
    for (int j = 0; j < 4; ++j)
      acc[i][j] = (floatx4){0.f, 0.f, 0.f, 0.f};

  stage_kh(0, 0); stage_kh(0, 1); stage_kh(1, 0);
  wait_vm<4>();
  bar();

  #pragma unroll
  for (int t = 0; t < 8; ++t) {
    const char* Ah = &smem[t & 1][wm][0];
    const char* Bh = &smem[t & 1][2 + (wn >> 1)][0] + (wn & 1) * 8192;
    #pragma unroll
    for (int kh = 0; kh < 2; ++kh) {
      short8 a[4], bb[4];
      if (kh == 0) { if (t < 7) stage_kh(t + 1, 1); }
      else         { if (t < 6) stage_kh(t + 2, 0); }
      #pragma unroll
      for (int fr = 0; fr < 4; ++fr)
        a[fr] = *(const short8*)(Ah + fr * 2048 + kh * 1024 + aoff);
      #pragma unroll
      for (int fn = 0; fn < 4; ++fn)
        bb[fn] = *(const short8*)(Bh + fn * 2048 + kh * 1024 + aoff);
      bar();
      asm volatile("s_waitcnt lgkmcnt(0)" ::: "memory");
      __builtin_amdgcn_sched_barrier(0);
      __builtin_amdgcn_s_setprio(1);
      #pragma unroll
      for (int fr = 0; fr < 4; ++fr)
        #pragma unroll
        for (int fn = 0; fn < 4; ++fn)
          acc[fr][fn] = __builtin_amdgcn_mfma_f32_16x16x32_bf16(
              a[fr], bb[fn], acc[fr][fn], 0, 0, 0);
      __builtin_amdgcn_s_setprio(0);
      bar();
      #pragma unroll
      for (int fr = 0; fr < 4; ++fr)
        a[fr] = *(const short8*)(Ah + (4 + fr) * 2048 + kh * 1024 + aoff);
      bar();
      asm volatile("s_waitcnt lgkmcnt(0)" ::: "memory");
      __builtin_amdgcn_sched_barrier(0);
      __builtin_amdgcn_s_setprio(1);
      #pragma unroll
      for (int fr = 0; fr < 4; ++fr)
        #pragma unroll
        for (int fn = 0; fn < 4; ++fn)
          acc[4 + fr][fn] = __builtin_amdgcn_mfma_f32_16x16x32_bf16(
              a[fr], bb[fn], acc[4 + fr][fn], 0, 0, 0);
      __builtin_amdgcn_s_setprio(0);
      if (kh == 1) {
        if (t < 6)       wait_vm<4>();
        else if (t == 6) wait_vm<0>();
      }
      bar();
    }
  }

  // epilogue: out = (acc + u[row] + v[col]) / 64, mask -> -inf
  float* ob = out + (size_t)b * 2048 * 4096
                  + ((size_t)mt * 256 + (size_t)wm * 128) * 4096
                  + (size_t)nt * 256 + wn * 64;
  const unsigned char* mb = mask + (size_t)b * 4096 + nt * 256 + wn * 64;
  const float* ub = u + (size_t)b * 2048 + mt * 256 + wm * 128;
  const float* vb = v + (size_t)b * 4096 + nt * 256 + wn * 64;
  float ur[8][4];
  #pragma unroll
  for (int f8 = 0; f8 < 8; ++f8)
    #pragma unroll
    for (int r = 0; r < 4; ++r)
      ur[f8][r] = ub[f8 * 16 + kg * 4 + r];
  #pragma unroll
  for (int fc = 0; fc < 4; ++fc) {
    const int c = fc * 16 + l15;
    const bool msk = mb[c] != 0;
    const float vc = vb[c];
    #pragma unroll
    for (int f8 = 0; f8 < 8; ++f8)
      #pragma unroll
      for (int r = 0; r < 4; ++r)
        ob[(size_t)(f8 * 16 + kg * 4 + r) * 4096 + c] =
            msk ? NEG_INF : (acc[f8][fc][r] + ur[f8][r] + vc) * (1.f / 64.f);
  }
}

extern "C" void kernel_launch(void* const* d_in, const int* in_sizes, int n_in,
                              void* d_out, int out_size, void* d_ws, size_t ws_size,
                              hipStream_t stream) {
  const float* query = (const float*)d_in[0];
  const float* keys  = (const float*)d_in[1];
  const unsigned char* mask = (const unsigned char*)d_in[2];  // numpy bool = 1B
  const float* q_w = (const float*)d_in[3];
  const float* q_b = (const float*)d_in[4];
  const float* k_w = (const float*)d_in[5];
  const float* k_b = (const float*)d_in[6];
  float* out = (float*)d_out;

  // workspace carve, ~34.2 MiB
  char* ws = (char*)d_ws;
  bf16*  x_bf  = (bf16*)(ws);                        //  8192*512 bf16
  bf16*  y_bf  = (bf16*)(ws + 8388608);              // 16384*512 bf16
  bf16*  mt_bf = (bf16*)(ws + 25165824);             //   512*512 bf16
  bf16*  z_bf  = (bf16*)(ws + 25690112);             //  8192*512 bf16
  float* u     = (float*)(ws + 34078720);            //  8192 f32
  float* v     = (float*)(ws + 34111488);            // 16384 f32
  float* w1    = (float*)(ws + 34177024);            //   512 f32
  float* w2    = (float*)(ws + 34179072);            //   512 f32
  float* cks   = (float*)(ws + 34181120);            //     1 f32

  prep<<<80, 256, 0, stream>>>(q_w, k_w, q_b, k_b, mt_bf, w1, w2, cks);
  cvt_in<<<6144, 256, 0, stream>>>(query, keys, w1, w2, cks, x_bf, y_bf, u, v);
  zgemm<<<dim3(64, 4), 256, 0, stream>>>(x_bf, mt_bf, z_bf);
  qk8<<<512, 512, 0, stream>>>(z_bf, y_bf, mask, u, v, out);
}